// Round 10
// baseline (1456.701 us; speedup 1.0000x reference)
//
#include <hip/hip_runtime.h>
#include <hip/hip_fp16.h>
#include <math.h>

// InstantNGP forward, level-blocked ("split") schedule v4:
//   cvt_tab:     fp32 table -> fp16 (half2/entry) in d_ws
//   contract_k:  contraction once -> cpos float3; ALSO dense levels 0..3 -> feats
//   enc_hash:    one pass per hashed level 4..15 (2 MiB fp16 slab L2-resident),
//                2 points/thread (16 gathers in flight; latency hiding)
//   mlp_k:       feats(16xhalf2) + SH -> 41->64->64->4 + head
//                waves_per_eu(2,4): stop compiler AGPR-parking h[64] (R9: 52 VGPR
//                + 2.2 VALU-ops/FMA = accvgpr shuffle; 460us vs 186us ideal)
// R6: fused kernel L2-miss-bound (FETCH 5.9GB @3.55TB/s). R9: split = 1428us,
// mlp_k 460us VALU-bound w/ AGPR movs, enc_hash ~75us/pass latency-bound.

#define TSIZE (1u << 19)
#define P1H 2654435761u
#define P2H 805459861u

__device__ __forceinline__ void contract_pt(float& px, float& py, float& pz) {
    float ax = fabsf(px), ay = fabsf(py), az = fabsf(pz);
    float m = fmaxf(ax, fmaxf(ay, az));
    float major = (ax >= ay && ax >= az) ? px : ((ay >= az) ? py : pz);
    bool inner = (m <= 4.0f);
    float sm = inner ? 1.0f : major;
    float nm = (sm > 0.0f) ? (2.0f - 4.0f / sm) : (-2.0f - 4.0f / sm);
    float ratio = nm / sm;
    float s = inner ? 0.25f : ratio;       // p/A == p*0.25
    px = (px * s + 2.0f) * 0.25f;          // (model+2)/4
    py = (py * s + 2.0f) * 0.25f;
    pz = (pz * s + 2.0f) * 0.25f;
}

// ---------------- split-path kernels ----------------

__global__ __launch_bounds__(256) void cvt_tab(const float2* __restrict__ tab,
                                               __half2* __restrict__ htab, int ntot)
{
    int i = blockIdx.x * blockDim.x + threadIdx.x;
    if (i < ntot) {
        float2 v = tab[i];
        htab[i] = __floats2half2_rn(v.x, v.y);
    }
}

// Contraction -> cpos (packed float3), plus dense levels 0..3 -> feats.
__global__ __launch_bounds__(256) void contract_k(const float* __restrict__ pos,
                                                  const float* __restrict__ tab,
                                                  float* __restrict__ cpos,
                                                  __half2* __restrict__ feats, int N)
{
    int n = blockIdx.x * blockDim.x + threadIdx.x;
    if (n >= N) return;
    float px = pos[3*n+0], py = pos[3*n+1], pz = pos[3*n+2];
    contract_pt(px, py, pz);
    cpos[3*n+0] = px; cpos[3*n+1] = py; cpos[3*n+2] = pz;

    const int RES_[4] = {16, 25, 41, 66};
    #pragma unroll
    for (int l = 0; l < 4; l++) {
        const int res = RES_[l];
        const unsigned r1 = (unsigned)(res + 1);
        float xx = px * (float)res, yy = py * (float)res, zz = pz * (float)res;
        float xf = floorf(xx), yf = floorf(yy), zf = floorf(zz);
        float wx1 = xx - xf, wy1 = yy - yf, wz1 = zz - zf;
        float wx0 = 1.0f - wx1, wy0 = 1.0f - wy1, wz0 = 1.0f - wz1;
        unsigned xi = (unsigned)xf, yi = (unsigned)yf, zi = (unsigned)zf;
        const float2* tl = (const float2*)tab + (size_t)l * TSIZE;
        unsigned ty0 = yi * r1, tz0 = zi * (r1 * r1);

        float2 v[8];
        #pragma unroll
        for (int c = 0; c < 8; c++) {
            unsigned idx = (xi + ((c & 1) ? 1u : 0u))
                         + (ty0 + ((c & 2) ? r1 : 0u))
                         + (tz0 + ((c & 4) ? r1 * r1 : 0u));
            v[c] = tl[idx];
        }
        float f0 = 0.0f, f1 = 0.0f;
        #pragma unroll
        for (int c = 0; c < 8; c++) {
            float wgt = ((c & 1) ? wx1 : wx0) * ((c & 2) ? wy1 : wy0)
                      * ((c & 4) ? wz1 : wz0);
            f0 = fmaf(wgt, v[c].x, f0);
            f1 = fmaf(wgt, v[c].y, f1);
        }
        feats[(size_t)l * N + n] = __floats2half2_rn(f0, f1);
    }
}

// One hashed level per pass; 2 points/thread (16 gathers in flight).
__global__ __launch_bounds__(256) void enc_hash(const float* __restrict__ cpos,
                                                const __half2* __restrict__ htab,
                                                __half2* __restrict__ feats,
                                                int level, int res, int N)
{
    int t = blockIdx.x * blockDim.x + threadIdx.x;
    int n0 = 2 * t;
    if (n0 >= N) return;   // N is even; n0+1 < N guaranteed

    float pxA = cpos[3*n0+0], pyA = cpos[3*n0+1], pzA = cpos[3*n0+2];
    float pxB = cpos[3*n0+3], pyB = cpos[3*n0+4], pzB = cpos[3*n0+5];
    const __half2* tl = htab + (size_t)level * TSIZE;
    const float fres = (float)res;

    // --- point A indices ---
    float xxA = pxA*fres, yyA = pyA*fres, zzA = pzA*fres;
    float xfA = floorf(xxA), yfA = floorf(yyA), zfA = floorf(zzA);
    unsigned xiA = (unsigned)xfA, yiA = (unsigned)yfA, ziA = (unsigned)zfA;
    unsigned tyA = yiA * P1H, tzA = ziA * P2H;
    // --- point B indices ---
    float xxB = pxB*fres, yyB = pyB*fres, zzB = pzB*fres;
    float xfB = floorf(xxB), yfB = floorf(yyB), zfB = floorf(zzB);
    unsigned xiB = (unsigned)xfB, yiB = (unsigned)yfB, ziB = (unsigned)zfB;
    unsigned tyB = yiB * P1H, tzB = ziB * P2H;

    // issue all 16 gathers (interleaved A/B) before any use
    __half2 vA[8], vB[8];
    #pragma unroll
    for (int c = 0; c < 8; c++) {
        unsigned iA = ((xiA + ((c & 1) ? 1u : 0u))
                     ^ (tyA + ((c & 2) ? P1H : 0u))
                     ^ (tzA + ((c & 4) ? P2H : 0u))) & (TSIZE - 1u);
        unsigned iB = ((xiB + ((c & 1) ? 1u : 0u))
                     ^ (tyB + ((c & 2) ? P1H : 0u))
                     ^ (tzB + ((c & 4) ? P2H : 0u))) & (TSIZE - 1u);
        vA[c] = tl[iA];
        vB[c] = tl[iB];
    }

    float wx1A = xxA - xfA, wy1A = yyA - yfA, wz1A = zzA - zfA;
    float wx0A = 1.0f - wx1A, wy0A = 1.0f - wy1A, wz0A = 1.0f - wz1A;
    float wx1B = xxB - xfB, wy1B = yyB - yfB, wz1B = zzB - zfB;
    float wx0B = 1.0f - wx1B, wy0B = 1.0f - wy1B, wz0B = 1.0f - wz1B;

    float f0A = 0.0f, f1A = 0.0f, f0B = 0.0f, f1B = 0.0f;
    #pragma unroll
    for (int c = 0; c < 8; c++) {
        float wA = ((c & 1) ? wx1A : wx0A) * ((c & 2) ? wy1A : wy0A)
                 * ((c & 4) ? wz1A : wz0A);
        float2 a = __half22float2(vA[c]);
        f0A = fmaf(wA, a.x, f0A);  f1A = fmaf(wA, a.y, f1A);
        float wB = ((c & 1) ? wx1B : wx0B) * ((c & 2) ? wy1B : wy0B)
                 * ((c & 4) ? wz1B : wz0B);
        float2 b = __half22float2(vB[c]);
        f0B = fmaf(wB, b.x, f0B);  f1B = fmaf(wB, b.y, f1B);
    }

    __half2 ha = __floats2half2_rn(f0A, f1A);
    __half2 hb = __floats2half2_rn(f0B, f1B);
    union { struct { __half2 a, b; } h; uint2 u; } pk;
    pk.h.a = ha; pk.h.b = hb;
    *reinterpret_cast<uint2*>(&feats[(size_t)level * N + n0]) = pk.u;  // 8B store
}

// Final MLP: VALU-bound. waves_per_eu(2,4): allow up to 256 VGPR, and remove
// any payoff for shrinking below 128 -> h[64] stays in arch VGPRs (no AGPR movs).
__global__ __attribute__((amdgpu_flat_work_group_size(256, 256),
                          amdgpu_waves_per_eu(2, 4)))
void mlp_k(const float* __restrict__ dirs,
           const __half2* __restrict__ feats,
           const float* __restrict__ W0,
           const float* __restrict__ W1,
           const float* __restrict__ W2,
           float* __restrict__ out, int N)
{
    int n = blockIdx.x * blockDim.x + threadIdx.x;
    if (n >= N) return;

    // Issue all 16 feature loads up front (16 coalesced streams in flight).
    __half2 f[16];
    #pragma unroll
    for (int l = 0; l < 16; l++) f[l] = feats[(size_t)l * N + n];
    float dx_ = dirs[3*n+0], dy_ = dirs[3*n+1], dz_ = dirs[3*n+2];

    float h[64];
    // SH rows 32..40 first (covers feature-load latency).
    {
        float s1 = -0.4886025119029199f * dy_;
        float s2 =  0.4886025119029199f * dz_;
        float s3 = -0.4886025119029199f * dx_;
        float s4 =  1.0925484305920792f * dx_ * dy_;
        float s5 = -1.0925484305920792f * dy_ * dz_;
        float s6 =  0.31539156525252005f * (2.0f*dz_*dz_ - dx_*dx_ - dy_*dy_);
        float s7 = -1.0925484305920792f * dx_ * dz_;
        float s8 =  0.5462742152960396f * (dx_*dx_ - dy_*dy_);
        #pragma unroll
        for (int j = 0; j < 64; j++) {
            float a = 0.28209479177387814f * W0[32*64 + j];
            a = fmaf(s1, W0[33*64 + j], a);
            a = fmaf(s2, W0[34*64 + j], a);
            a = fmaf(s3, W0[35*64 + j], a);
            a = fmaf(s4, W0[36*64 + j], a);
            a = fmaf(s5, W0[37*64 + j], a);
            a = fmaf(s6, W0[38*64 + j], a);
            a = fmaf(s7, W0[39*64 + j], a);
            a = fmaf(s8, W0[40*64 + j], a);
            h[j] = a;
        }
    }
    #pragma unroll
    for (int l = 0; l < 16; l++) {
        float2 fv = __half22float2(f[l]);
        #pragma unroll
        for (int j = 0; j < 64; j++)
            h[j] = fmaf(fv.y, W0[(2*l+1)*64 + j], fmaf(fv.x, W0[(2*l)*64 + j], h[j]));
    }
    #pragma unroll
    for (int j = 0; j < 64; j++) h[j] = fmaxf(h[j], 0.0f);

    float o0 = 0.0f, o1 = 0.0f, o2 = 0.0f, o3 = 0.0f;
    #pragma unroll
    for (int jt = 0; jt < 4; jt++) {
        float h2[16];
        #pragma unroll
        for (int j = 0; j < 16; j++) h2[j] = 0.0f;
        #pragma unroll
        for (int i = 0; i < 64; i++) {
            const float e = h[i];
            #pragma unroll
            for (int j = 0; j < 16; j++) h2[j] = fmaf(e, W1[i*64 + jt*16 + j], h2[j]);
        }
        #pragma unroll
        for (int j = 0; j < 16; j++) {
            float val = fmaxf(h2[j], 0.0f);
            o0 = fmaf(val, W2[(jt*16 + j)*4 + 0], o0);
            o1 = fmaf(val, W2[(jt*16 + j)*4 + 1], o1);
            o2 = fmaf(val, W2[(jt*16 + j)*4 + 2], o2);
            o3 = fmaf(val, W2[(jt*16 + j)*4 + 3], o3);
        }
    }

    float density = fminf(expf(o0), fmaxf(o0, 0.0f) + 1000000.0f);
    float r = 1.0f / (1.0f + expf(-o1));
    float g = 1.0f / (1.0f + expf(-o2));
    float b = 1.0f / (1.0f + expf(-o3));
    *reinterpret_cast<float4*>(out + 4*(size_t)n) = make_float4(density, r, g, b);
}

// ---------------- fallback: R6 fused kernel (passed; unchanged) ----------------

#define NGP_LOAD(l, b) do {                                                   \
    const int res = RES_[(l)];                                                \
    const bool dense = ((l) < 4);                                             \
    float xx = px * (float)res, yy = py * (float)res, zz = pz * (float)res;   \
    unsigned xi = (unsigned)floorf(xx), yi = (unsigned)floorf(yy),            \
             zi = (unsigned)floorf(zz);                                       \
    const float2* tl = (const float2*)tab + (size_t)(l) * TSIZE;              \
    unsigned tx0, tx1, ty0, ty1, tz0, tz1;                                    \
    if (dense) {                                                              \
        const unsigned r1 = (unsigned)(res + 1);                              \
        tx0 = xi;           tx1 = xi + 1u;                                    \
        ty0 = yi * r1;      ty1 = ty0 + r1;                                   \
        tz0 = zi * (r1*r1); tz1 = tz0 + (r1*r1);                              \
    } else {                                                                  \
        tx0 = xi;               tx1 = xi + 1u;                                \
        ty0 = yi * P1H;         ty1 = ty0 + P1H;                              \
        tz0 = zi * P2H;         tz1 = tz0 + P2H;                              \
    }                                                                         \
    _Pragma("unroll")                                                         \
    for (int c = 0; c < 8; c++) {                                             \
        unsigned tx = (c & 1) ? tx1 : tx0;                                    \
        unsigned ty = (c & 2) ? ty1 : ty0;                                    \
        unsigned tz = (c & 4) ? tz1 : tz0;                                    \
        unsigned idx = dense ? (tx + ty + tz)                                 \
                             : ((tx ^ ty ^ tz) & (TSIZE - 1u));               \
        v[b][c] = tl[idx];                                                    \
    }                                                                         \
} while (0)

#define NGP_ACC(l, b) do {                                                    \
    const int res = RES_[(l)];                                                \
    float xx = px * (float)res, yy = py * (float)res, zz = pz * (float)res;   \
    float wx1 = xx - floorf(xx), wy1 = yy - floorf(yy), wz1 = zz - floorf(zz);\
    float wx0 = 1.0f - wx1, wy0 = 1.0f - wy1, wz0 = 1.0f - wz1;               \
    float f0 = 0.0f, f1 = 0.0f;                                               \
    _Pragma("unroll")                                                         \
    for (int c = 0; c < 8; c++) {                                             \
        float wgt = ((c & 1) ? wx1 : wx0) * ((c & 2) ? wy1 : wy0)             \
                  * ((c & 4) ? wz1 : wz0);                                    \
        f0 = fmaf(wgt, v[b][c].x, f0);                                        \
        f1 = fmaf(wgt, v[b][c].y, f1);                                        \
    }                                                                         \
    _Pragma("unroll")                                                         \
    for (int j = 0; j < 64; j++) {                                            \
        h[j] = fmaf(f1, W0[(2*(l)+1)*64 + j], fmaf(f0, W0[(2*(l))*64 + j], h[j])); \
    }                                                                         \
} while (0)

__global__ __launch_bounds__(256, 4) void ngp_fwd(
                        const float* __restrict__ pos,
                        const float* __restrict__ dirs,
                        const float* __restrict__ tab,
                        const float* __restrict__ W0,
                        const float* __restrict__ W1,
                        const float* __restrict__ W2,
                        float* __restrict__ out,
                        int N)
{
    int n = blockIdx.x * blockDim.x + threadIdx.x;
    if (n >= N) return;
    const int RES_[16] = {16,25,41,66,107,173,279,450,725,1169,1883,3035,4889,7877,12689,20443};
    float px = pos[3*n+0], py = pos[3*n+1], pz = pos[3*n+2];
    float dx_ = dirs[3*n+0], dy_ = dirs[3*n+1], dz_ = dirs[3*n+2];
    contract_pt(px, py, pz);

    float2 v[2][8];
    float  h[64];
    NGP_LOAD(4, 0);
    NGP_LOAD(5, 1);
    {
        float s1 = -0.4886025119029199f * dy_;
        float s2 =  0.4886025119029199f * dz_;
        float s3 = -0.4886025119029199f * dx_;
        float s4 =  1.0925484305920792f * dx_ * dy_;
        float s5 = -1.0925484305920792f * dy_ * dz_;
        float s6 =  0.31539156525252005f * (2.0f*dz_*dz_ - dx_*dx_ - dy_*dy_);
        float s7 = -1.0925484305920792f * dx_ * dz_;
        float s8 =  0.5462742152960396f * (dx_*dx_ - dy_*dy_);
        #pragma unroll
        for (int j = 0; j < 64; j++) {
            float a = 0.28209479177387814f * W0[32*64 + j];
            a = fmaf(s1, W0[33*64 + j], a);
            a = fmaf(s2, W0[34*64 + j], a);
            a = fmaf(s3, W0[35*64 + j], a);
            a = fmaf(s4, W0[36*64 + j], a);
            a = fmaf(s5, W0[37*64 + j], a);
            a = fmaf(s6, W0[38*64 + j], a);
            a = fmaf(s7, W0[39*64 + j], a);
            a = fmaf(s8, W0[40*64 + j], a);
            h[j] = a;
        }
    }
    NGP_ACC(4, 0);   NGP_LOAD(6, 0);
    NGP_ACC(5, 1);   NGP_LOAD(7, 1);
    NGP_ACC(6, 0);   NGP_LOAD(8, 0);
    NGP_ACC(7, 1);   NGP_LOAD(9, 1);
    NGP_ACC(8, 0);   NGP_LOAD(10, 0);
    NGP_ACC(9, 1);   NGP_LOAD(11, 1);
    NGP_ACC(10, 0);  NGP_LOAD(12, 0);
    NGP_ACC(11, 1);  NGP_LOAD(13, 1);
    NGP_ACC(12, 0);  NGP_LOAD(14, 0);
    NGP_ACC(13, 1);  NGP_LOAD(15, 1);
    NGP_ACC(14, 0);  NGP_LOAD(0, 0);
    NGP_ACC(15, 1);  NGP_LOAD(1, 1);
    NGP_ACC(0, 0);   NGP_LOAD(2, 0);
    NGP_ACC(1, 1);   NGP_LOAD(3, 1);
    NGP_ACC(2, 0);
    NGP_ACC(3, 1);

    #pragma unroll
    for (int j = 0; j < 64; j++) h[j] = fmaxf(h[j], 0.0f);

    float o0 = 0.0f, o1 = 0.0f, o2 = 0.0f, o3 = 0.0f;
    #pragma unroll
    for (int jt = 0; jt < 4; jt++) {
        float h2[16];
        #pragma unroll
        for (int j = 0; j < 16; j++) h2[j] = 0.0f;
        #pragma unroll
        for (int i = 0; i < 64; i++) {
            const float e = h[i];
            #pragma unroll
            for (int j = 0; j < 16; j++) h2[j] = fmaf(e, W1[i*64 + jt*16 + j], h2[j]);
        }
        #pragma unroll
        for (int j = 0; j < 16; j++) {
            float val = fmaxf(h2[j], 0.0f);
            o0 = fmaf(val, W2[(jt*16 + j)*4 + 0], o0);
            o1 = fmaf(val, W2[(jt*16 + j)*4 + 1], o1);
            o2 = fmaf(val, W2[(jt*16 + j)*4 + 2], o2);
            o3 = fmaf(val, W2[(jt*16 + j)*4 + 3], o3);
        }
    }

    float density = fminf(expf(o0), fmaxf(o0, 0.0f) + 1000000.0f);
    float r = 1.0f / (1.0f + expf(-o1));
    float g = 1.0f / (1.0f + expf(-o2));
    float b = 1.0f / (1.0f + expf(-o3));
    *reinterpret_cast<float4*>(out + 4*(size_t)n) = make_float4(density, r, g, b);
}

// ---------------- launcher ----------------

extern "C" void kernel_launch(void* const* d_in, const int* in_sizes, int n_in,
                              void* d_out, int out_size, void* d_ws, size_t ws_size,
                              hipStream_t stream) {
    const float* pos = (const float*)d_in[0];
    const float* dir = (const float*)d_in[1];
    const float* tab = (const float*)d_in[2];
    const float* W0  = (const float*)d_in[3];
    const float* W1  = (const float*)d_in[4];
    const float* W2  = (const float*)d_in[5];
    float* out = (float*)d_out;

    const int N = in_sizes[0] / 3;
    const int RES_H[16] = {16,25,41,66,107,173,279,450,725,1169,1883,3035,4889,7877,12689,20443};

    const size_t htab_bytes  = (size_t)16 * TSIZE * 4;   // half2 per entry: 32 MB
    const size_t cpos_bytes  = (size_t)N * 12;           // packed float3: 24 MB
    const size_t feats_bytes = (size_t)16 * N * 4;       // half2 per level: 134 MB
    const size_t need = htab_bytes + cpos_bytes + feats_bytes;

    dim3 block(256);
    dim3 gridN((N + 255) / 256);
    dim3 gridN2((N/2 + 255) / 256);

    if (ws_size >= need) {
        __half2* htab  = (__half2*)d_ws;
        float*   cpos  = (float*)((char*)d_ws + htab_bytes);
        __half2* feats = (__half2*)((char*)d_ws + htab_bytes + cpos_bytes);

        const int ntot = 16 * (int)TSIZE;
        hipLaunchKernelGGL(cvt_tab, dim3((ntot + 255) / 256), block, 0, stream,
                           (const float2*)tab, htab, ntot);
        hipLaunchKernelGGL(contract_k, gridN, block, 0, stream, pos, tab, cpos, feats, N);
        for (int l = 4; l < 16; l++)
            hipLaunchKernelGGL(enc_hash, gridN2, block, 0, stream,
                               cpos, htab, feats, l, RES_H[l], N);
        hipLaunchKernelGGL(mlp_k, gridN, block, 0, stream,
                           dir, feats, W0, W1, W2, out, N);
    } else {
        hipLaunchKernelGGL(ngp_fwd, gridN, block, 0, stream,
                           pos, dir, tab, W0, W1, W2, out, N);
    }
}

// Round 12
// 1375.157 us; speedup vs baseline: 1.0593x; 1.0593x over previous
//
#include <hip/hip_runtime.h>
#include <hip/hip_fp16.h>
#include <math.h>

// InstantNGP forward, level-blocked ("split") schedule v5 (R10 resubmit, re-audited):
//   cvt_tab:     fp32 table -> fp16 (half2/entry) in d_ws
//   contract_k:  contraction once -> cpos float3; ALSO dense levels 0..3 -> feats
//   enc_hash:    one pass per hashed level 4..15 (2 MiB fp16 slab L2-resident)
//   mlp_k:       v_pk_fma_f32 inline-asm MLP. R9/R10: compiler parked h[64] in
//                AGPRs (52 arch VGPR, 2.2 VALU-ops/FMA shuffle, 460us vs 186us
//                scalar floor). pk_fma halves issue count (fp32 peak 157TF = 2x
//                scalar rate REQUIRES packed) and "+v" forces arch VGPRs.
// R6: fused kernel L2-miss-bound (FETCH 5.9GB @3.55TB/s). R9: split=1428us
// (mlp_k 460us, encode ~968us). R10: 2pt/thread enc_hash neutral -> reverted.

#define TSIZE (1u << 19)
#define P1H 2654435761u
#define P2H 805459861u

typedef float v2f __attribute__((ext_vector_type(2)));

// v_pk_fma_f32 D, S0, S1, S2 : per-lane D = S0*S1 + S2 (2x f32).
// LO: both result lanes use LOW half of %2; HI: both use HIGH half.
// op_sel[i] feeds the low result lane, op_sel_hi[i] the high lane.
#define PK_FMA_LO(acc, w, s1v) \
    asm("v_pk_fma_f32 %0, %1, %2, %0 op_sel:[0,0,0] op_sel_hi:[1,0,1]" \
        : "+v"(acc) : "s"(w), "v"(s1v))
#define PK_FMA_HI(acc, w, s1v) \
    asm("v_pk_fma_f32 %0, %1, %2, %0 op_sel:[0,1,0] op_sel_hi:[1,1,1]" \
        : "+v"(acc) : "s"(w), "v"(s1v))

__device__ __forceinline__ void contract_pt(float& px, float& py, float& pz) {
    float ax = fabsf(px), ay = fabsf(py), az = fabsf(pz);
    float m = fmaxf(ax, fmaxf(ay, az));
    float major = (ax >= ay && ax >= az) ? px : ((ay >= az) ? py : pz);
    bool inner = (m <= 4.0f);
    float sm = inner ? 1.0f : major;
    float nm = (sm > 0.0f) ? (2.0f - 4.0f / sm) : (-2.0f - 4.0f / sm);
    float ratio = nm / sm;
    float s = inner ? 0.25f : ratio;       // p/A == p*0.25
    px = (px * s + 2.0f) * 0.25f;          // (model+2)/4
    py = (py * s + 2.0f) * 0.25f;
    pz = (pz * s + 2.0f) * 0.25f;
}

// ---------------- split-path kernels ----------------

__global__ __launch_bounds__(256) void cvt_tab(const float2* __restrict__ tab,
                                               __half2* __restrict__ htab, int ntot)
{
    int i = blockIdx.x * blockDim.x + threadIdx.x;
    if (i < ntot) {
        float2 v = tab[i];
        htab[i] = __floats2half2_rn(v.x, v.y);
    }
}

// Contraction -> cpos (packed float3), plus dense levels 0..3 -> feats.
__global__ __launch_bounds__(256) void contract_k(const float* __restrict__ pos,
                                                  const float* __restrict__ tab,
                                                  float* __restrict__ cpos,
                                                  __half2* __restrict__ feats, int N)
{
    int n = blockIdx.x * blockDim.x + threadIdx.x;
    if (n >= N) return;
    float px = pos[3*n+0], py = pos[3*n+1], pz = pos[3*n+2];
    contract_pt(px, py, pz);
    cpos[3*n+0] = px; cpos[3*n+1] = py; cpos[3*n+2] = pz;

    const int RES_[4] = {16, 25, 41, 66};
    #pragma unroll
    for (int l = 0; l < 4; l++) {
        const int res = RES_[l];
        const unsigned r1 = (unsigned)(res + 1);
        float xx = px * (float)res, yy = py * (float)res, zz = pz * (float)res;
        float xf = floorf(xx), yf = floorf(yy), zf = floorf(zz);
        float wx1 = xx - xf, wy1 = yy - yf, wz1 = zz - zf;
        float wx0 = 1.0f - wx1, wy0 = 1.0f - wy1, wz0 = 1.0f - wz1;
        unsigned xi = (unsigned)xf, yi = (unsigned)yf, zi = (unsigned)zf;
        const float2* tl = (const float2*)tab + (size_t)l * TSIZE;
        unsigned ty0 = yi * r1, tz0 = zi * (r1 * r1);

        float2 v[8];
        #pragma unroll
        for (int c = 0; c < 8; c++) {
            unsigned idx = (xi + ((c & 1) ? 1u : 0u))
                         + (ty0 + ((c & 2) ? r1 : 0u))
                         + (tz0 + ((c & 4) ? r1 * r1 : 0u));
            v[c] = tl[idx];
        }
        float f0 = 0.0f, f1 = 0.0f;
        #pragma unroll
        for (int c = 0; c < 8; c++) {
            float wgt = ((c & 1) ? wx1 : wx0) * ((c & 2) ? wy1 : wy0)
                      * ((c & 4) ? wz1 : wz0);
            f0 = fmaf(wgt, v[c].x, f0);
            f1 = fmaf(wgt, v[c].y, f1);
        }
        feats[(size_t)l * N + n] = __floats2half2_rn(f0, f1);
    }
}

// One hashed level per pass: fp16 slab (2 MiB) stays L2-resident for the pass.
__global__ __launch_bounds__(256) void enc_hash(const float* __restrict__ cpos,
                                                const __half2* __restrict__ htab,
                                                __half2* __restrict__ feats,
                                                int level, int res, int N)
{
    int n = blockIdx.x * blockDim.x + threadIdx.x;
    if (n >= N) return;
    float px = cpos[3*n+0], py = cpos[3*n+1], pz = cpos[3*n+2];

    float xx = px * (float)res, yy = py * (float)res, zz = pz * (float)res;
    float xf = floorf(xx), yf = floorf(yy), zf = floorf(zz);
    float wx1 = xx - xf, wy1 = yy - yf, wz1 = zz - zf;
    float wx0 = 1.0f - wx1, wy0 = 1.0f - wy1, wz0 = 1.0f - wz1;
    unsigned xi = (unsigned)xf, yi = (unsigned)yf, zi = (unsigned)zf;
    const __half2* tl = htab + (size_t)level * TSIZE;
    unsigned ty0 = yi * P1H, tz0 = zi * P2H;

    __half2 v[8];
    #pragma unroll
    for (int c = 0; c < 8; c++) {
        unsigned tx = xi + ((c & 1) ? 1u : 0u);
        unsigned ty = ty0 + ((c & 2) ? P1H : 0u);
        unsigned tz = tz0 + ((c & 4) ? P2H : 0u);
        unsigned idx = (tx ^ ty ^ tz) & (TSIZE - 1u);
        v[c] = tl[idx];
    }
    float f0 = 0.0f, f1 = 0.0f;
    #pragma unroll
    for (int c = 0; c < 8; c++) {
        float2 vv = __half22float2(v[c]);
        float wgt = ((c & 1) ? wx1 : wx0) * ((c & 2) ? wy1 : wy0)
                  * ((c & 4) ? wz1 : wz0);
        f0 = fmaf(wgt, vv.x, f0);
        f1 = fmaf(wgt, vv.y, f1);
    }
    feats[(size_t)level * N + n] = __floats2half2_rn(f0, f1);
}

// Final MLP via v_pk_fma_f32 (packed fp32: 2 FMA/instr, forced arch VGPRs).
__global__ __launch_bounds__(256, 2) void mlp_k(const float* __restrict__ dirs,
                                                const __half2* __restrict__ feats,
                                                const float* __restrict__ W0,
                                                const float* __restrict__ W1,
                                                const float* __restrict__ W2,
                                                float* __restrict__ out, int N)
{
    int n = blockIdx.x * blockDim.x + threadIdx.x;
    if (n >= N) return;

    const v2f* W0v = (const v2f*)W0;   // [41 rows][32 pairs]
    const v2f* W1v = (const v2f*)W1;   // [64 rows][32 pairs]
    const v2f* W2v = (const v2f*)W2;   // [64 rows][2 pairs]

    // Issue all 16 feature loads up front (coalesced streams in flight).
    __half2 f[16];
    #pragma unroll
    for (int l = 0; l < 16; l++) f[l] = feats[(size_t)l * N + n];
    float dx_ = dirs[3*n+0], dy_ = dirs[3*n+1], dz_ = dirs[3*n+2];

    // h as 32 register pairs; zero-init then accumulate all 41 rows via pk_fma.
    v2f hv[32];
    #pragma unroll
    for (int k = 0; k < 32; k++) hv[k] = (v2f)(0.0f);

    // SH rows 32..40 (9 rows packed as 5 lane-value pairs).
    {
        float s1 = -0.4886025119029199f * dy_;
        float s2 =  0.4886025119029199f * dz_;
        float s3 = -0.4886025119029199f * dx_;
        float s4 =  1.0925484305920792f * dx_ * dy_;
        float s5 = -1.0925484305920792f * dy_ * dz_;
        float s6 =  0.31539156525252005f * (2.0f*dz_*dz_ - dx_*dx_ - dy_*dy_);
        float s7 = -1.0925484305920792f * dx_ * dz_;
        float s8 =  0.5462742152960396f * (dx_*dx_ - dy_*dy_);
        v2f p0 = {0.28209479177387814f, s1};
        v2f p1 = {s2, s3};
        v2f p2 = {s4, s5};
        v2f p3 = {s6, s7};
        v2f p4 = {s8, 0.0f};
        #pragma unroll
        for (int k = 0; k < 32; k++) {
            PK_FMA_LO(hv[k], W0v[32*32 + k], p0);
            PK_FMA_HI(hv[k], W0v[33*32 + k], p0);
            PK_FMA_LO(hv[k], W0v[34*32 + k], p1);
            PK_FMA_HI(hv[k], W0v[35*32 + k], p1);
            PK_FMA_LO(hv[k], W0v[36*32 + k], p2);
            PK_FMA_HI(hv[k], W0v[37*32 + k], p2);
            PK_FMA_LO(hv[k], W0v[38*32 + k], p3);
            PK_FMA_HI(hv[k], W0v[39*32 + k], p3);
            PK_FMA_LO(hv[k], W0v[40*32 + k], p4);
        }
    }

    // Hash-grid rows 0..31: per level, rows 2l (feat.x) and 2l+1 (feat.y).
    #pragma unroll
    for (int l = 0; l < 16; l++) {
        float2 fv = __half22float2(f[l]);
        v2f fp = {fv.x, fv.y};
        #pragma unroll
        for (int k = 0; k < 32; k++) {
            PK_FMA_LO(hv[k], W0v[(2*l  )*32 + k], fp);
            PK_FMA_HI(hv[k], W0v[(2*l+1)*32 + k], fp);
        }
    }

    // relu
    #pragma unroll
    for (int k = 0; k < 32; k++) {
        hv[k].x = fmaxf(hv[k].x, 0.0f);
        hv[k].y = fmaxf(hv[k].y, 0.0f);
    }

    // Layers 1+2 fused, 16-wide tiles (8 pairs of h2 live).
    v2f o01 = (v2f)(0.0f), o23 = (v2f)(0.0f);
    #pragma unroll
    for (int jt = 0; jt < 4; jt++) {
        v2f h2v[8];
        #pragma unroll
        for (int k = 0; k < 8; k++) h2v[k] = (v2f)(0.0f);
        #pragma unroll
        for (int i = 0; i < 64; i++) {
            #pragma unroll
            for (int k = 0; k < 8; k++) {
                if (i & 1) { PK_FMA_HI(h2v[k], W1v[i*32 + jt*8 + k], hv[i>>1]); }
                else       { PK_FMA_LO(h2v[k], W1v[i*32 + jt*8 + k], hv[i>>1]); }
            }
        }
        #pragma unroll
        for (int k = 0; k < 8; k++) {
            float a = fmaxf(h2v[k].x, 0.0f);
            float b = fmaxf(h2v[k].y, 0.0f);
            v2f t = {a, b};
            const int r0 = jt*16 + 2*k;        // W2 rows r0 (lane a), r0+1 (lane b)
            PK_FMA_LO(o01, W2v[r0*2 + 0], t);
            PK_FMA_LO(o23, W2v[r0*2 + 1], t);
            PK_FMA_HI(o01, W2v[(r0+1)*2 + 0], t);
            PK_FMA_HI(o23, W2v[(r0+1)*2 + 1], t);
        }
    }

    float o0 = o01.x, o1 = o01.y, o2 = o23.x, o3 = o23.y;
    float density = fminf(expf(o0), fmaxf(o0, 0.0f) + 1000000.0f);
    float r = 1.0f / (1.0f + expf(-o1));
    float g = 1.0f / (1.0f + expf(-o2));
    float b = 1.0f / (1.0f + expf(-o3));
    *reinterpret_cast<float4*>(out + 4*(size_t)n) = make_float4(density, r, g, b);
}

// ---------------- fallback: R6 fused kernel (passed; unchanged) ----------------

#define NGP_LOAD(l, b) do {                                                   \
    const int res = RES_[(l)];                                                \
    const bool dense = ((l) < 4);                                             \
    float xx = px * (float)res, yy = py * (float)res, zz = pz * (float)res;   \
    unsigned xi = (unsigned)floorf(xx), yi = (unsigned)floorf(yy),            \
             zi = (unsigned)floorf(zz);                                       \
    const float2* tl = (const float2*)tab + (size_t)(l) * TSIZE;              \
    unsigned tx0, tx1, ty0, ty1, tz0, tz1;                                    \
    if (dense) {                                                              \
        const unsigned r1 = (unsigned)(res + 1);                              \
        tx0 = xi;           tx1 = xi + 1u;                                    \
        ty0 = yi * r1;      ty1 = ty0 + r1;                                   \
        tz0 = zi * (r1*r1); tz1 = tz0 + (r1*r1);                              \
    } else {                                                                  \
        tx0 = xi;               tx1 = xi + 1u;                                \
        ty0 = yi * P1H;         ty1 = ty0 + P1H;                              \
        tz0 = zi * P2H;         tz1 = tz0 + P2H;                              \
    }                                                                         \
    _Pragma("unroll")                                                         \
    for (int c = 0; c < 8; c++) {                                             \
        unsigned tx = (c & 1) ? tx1 : tx0;                                    \
        unsigned ty = (c & 2) ? ty1 : ty0;                                    \
        unsigned tz = (c & 4) ? tz1 : tz0;                                    \
        unsigned idx = dense ? (tx + ty + tz)                                 \
                             : ((tx ^ ty ^ tz) & (TSIZE - 1u));               \
        v[b][c] = tl[idx];                                                    \
    }                                                                         \
} while (0)

#define NGP_ACC(l, b) do {                                                    \
    const int res = RES_[(l)];                                                \
    float xx = px * (float)res, yy = py * (float)res, zz = pz * (float)res;   \
    float wx1 = xx - floorf(xx), wy1 = yy - floorf(yy), wz1 = zz - floorf(zz);\
    float wx0 = 1.0f - wx1, wy0 = 1.0f - wy1, wz0 = 1.0f - wz1;               \
    float f0 = 0.0f, f1 = 0.0f;                                               \
    _Pragma("unroll")                                                         \
    for (int c = 0; c < 8; c++) {                                             \
        float wgt = ((c & 1) ? wx1 : wx0) * ((c & 2) ? wy1 : wy0)             \
                  * ((c & 4) ? wz1 : wz0);                                    \
        f0 = fmaf(wgt, v[b][c].x, f0);                                        \
        f1 = fmaf(wgt, v[b][c].y, f1);                                        \
    }                                                                         \
    _Pragma("unroll")                                                         \
    for (int j = 0; j < 64; j++) {                                            \
        h[j] = fmaf(f1, W0[(2*(l)+1)*64 + j], fmaf(f0, W0[(2*(l))*64 + j], h[j])); \
    }                                                                         \
} while (0)

__global__ __launch_bounds__(256, 4) void ngp_fwd(
                        const float* __restrict__ pos,
                        const float* __restrict__ dirs,
                        const float* __restrict__ tab,
                        const float* __restrict__ W0,
                        const float* __restrict__ W1,
                        const float* __restrict__ W2,
                        float* __restrict__ out,
                        int N)
{
    int n = blockIdx.x * blockDim.x + threadIdx.x;
    if (n >= N) return;
    const int RES_[16] = {16,25,41,66,107,173,279,450,725,1169,1883,3035,4889,7877,12689,20443};
    float px = pos[3*n+0], py = pos[3*n+1], pz = pos[3*n+2];
    float dx_ = dirs[3*n+0], dy_ = dirs[3*n+1], dz_ = dirs[3*n+2];
    contract_pt(px, py, pz);

    float2 v[2][8];
    float  h[64];
    NGP_LOAD(4, 0);
    NGP_LOAD(5, 1);
    {
        float s1 = -0.4886025119029199f * dy_;
        float s2 =  0.4886025119029199f * dz_;
        float s3 = -0.4886025119029199f * dx_;
        float s4 =  1.0925484305920792f * dx_ * dy_;
        float s5 = -1.0925484305920792f * dy_ * dz_;
        float s6 =  0.31539156525252005f * (2.0f*dz_*dz_ - dx_*dx_ - dy_*dy_);
        float s7 = -1.0925484305920792f * dx_ * dz_;
        float s8 =  0.5462742152960396f * (dx_*dx_ - dy_*dy_);
        #pragma unroll
        for (int j = 0; j < 64; j++) {
            float a = 0.28209479177387814f * W0[32*64 + j];
            a = fmaf(s1, W0[33*64 + j], a);
            a = fmaf(s2, W0[34*64 + j], a);
            a = fmaf(s3, W0[35*64 + j], a);
            a = fmaf(s4, W0[36*64 + j], a);
            a = fmaf(s5, W0[37*64 + j], a);
            a = fmaf(s6, W0[38*64 + j], a);
            a = fmaf(s7, W0[39*64 + j], a);
            a = fmaf(s8, W0[40*64 + j], a);
            h[j] = a;
        }
    }
    NGP_ACC(4, 0);   NGP_LOAD(6, 0);
    NGP_ACC(5, 1);   NGP_LOAD(7, 1);
    NGP_ACC(6, 0);   NGP_LOAD(8, 0);
    NGP_ACC(7, 1);   NGP_LOAD(9, 1);
    NGP_ACC(8, 0);   NGP_LOAD(10, 0);
    NGP_ACC(9, 1);   NGP_LOAD(11, 1);
    NGP_ACC(10, 0);  NGP_LOAD(12, 0);
    NGP_ACC(11, 1);  NGP_LOAD(13, 1);
    NGP_ACC(12, 0);  NGP_LOAD(14, 0);
    NGP_ACC(13, 1);  NGP_LOAD(15, 1);
    NGP_ACC(14, 0);  NGP_LOAD(0, 0);
    NGP_ACC(15, 1);  NGP_LOAD(1, 1);
    NGP_ACC(0, 0);   NGP_LOAD(2, 0);
    NGP_ACC(1, 1);   NGP_LOAD(3, 1);
    NGP_ACC(2, 0);
    NGP_ACC(3, 1);

    #pragma unroll
    for (int j = 0; j < 64; j++) h[j] = fmaxf(h[j], 0.0f);

    float o0 = 0.0f, o1 = 0.0f, o2 = 0.0f, o3 = 0.0f;
    #pragma unroll
    for (int jt = 0; jt < 4; jt++) {
        float h2[16];
        #pragma unroll
        for (int j = 0; j < 16; j++) h2[j] = 0.0f;
        #pragma unroll
        for (int i = 0; i < 64; i++) {
            const float e = h[i];
            #pragma unroll
            for (int j = 0; j < 16; j++) h2[j] = fmaf(e, W1[i*64 + jt*16 + j], h2[j]);
        }
        #pragma unroll
        for (int j = 0; j < 16; j++) {
            float val = fmaxf(h2[j], 0.0f);
            o0 = fmaf(val, W2[(jt*16 + j)*4 + 0], o0);
            o1 = fmaf(val, W2[(jt*16 + j)*4 + 1], o1);
            o2 = fmaf(val, W2[(jt*16 + j)*4 + 2], o2);
            o3 = fmaf(val, W2[(jt*16 + j)*4 + 3], o3);
        }
    }

    float density = fminf(expf(o0), fmaxf(o0, 0.0f) + 1000000.0f);
    float r = 1.0f / (1.0f + expf(-o1));
    float g = 1.0f / (1.0f + expf(-o2));
    float b = 1.0f / (1.0f + expf(-o3));
    *reinterpret_cast<float4*>(out + 4*(size_t)n) = make_float4(density, r, g, b);
}

// ---------------- launcher ----------------

extern "C" void kernel_launch(void* const* d_in, const int* in_sizes, int n_in,
                              void* d_out, int out_size, void* d_ws, size_t ws_size,
                              hipStream_t stream) {
    const float* pos = (const float*)d_in[0];
    const float* dir = (const float*)d_in[1];
    const float* tab = (const float*)d_in[2];
    const float* W0  = (const float*)d_in[3];
    const float* W1  = (const float*)d_in[4];
    const float* W2  = (const float*)d_in[5];
    float* out = (float*)d_out;

    const int N = in_sizes[0] / 3;
    const int RES_H[16] = {16,25,41,66,107,173,279,450,725,1169,1883,3035,4889,7877,12689,20443};

    const size_t htab_bytes  = (size_t)16 * TSIZE * 4;   // half2 per entry: 32 MB
    const size_t cpos_bytes  = (size_t)N * 12;           // packed float3: 24 MB
    const size_t feats_bytes = (size_t)16 * N * 4;       // half2 per level: 134 MB
    const size_t need = htab_bytes + cpos_bytes + feats_bytes;

    dim3 block(256);
    dim3 gridN((N + 255) / 256);

    if (ws_size >= need) {
        __half2* htab  = (__half2*)d_ws;
        float*   cpos  = (float*)((char*)d_ws + htab_bytes);
        __half2* feats = (__half2*)((char*)d_ws + htab_bytes + cpos_bytes);

        const int ntot = 16 * (int)TSIZE;
        hipLaunchKernelGGL(cvt_tab, dim3((ntot + 255) / 256), block, 0, stream,
                           (const float2*)tab, htab, ntot);
        hipLaunchKernelGGL(contract_k, gridN, block, 0, stream, pos, tab, cpos, feats, N);
        for (int l = 4; l < 16; l++)
            hipLaunchKernelGGL(enc_hash, gridN, block, 0, stream,
                               cpos, htab, feats, l, RES_H[l], N);
        hipLaunchKernelGGL(mlp_k, gridN, block, 0, stream,
                           dir, feats, W0, W1, W2, out, N);
    } else {
        hipLaunchKernelGGL(ngp_fwd, gridN, block, 0, stream,
                           pos, dir, tab, W0, W1, W2, out, N);
    }
}